// Round 1
// baseline (537.677 us; speedup 1.0000x reference)
//
#include <hip/hip_runtime.h>
#include <hip/hip_bf16.h>
#include <cstdint>
#include <cstddef>

typedef unsigned short u16;
typedef __attribute__((ext_vector_type(4))) unsigned short u16x4;
typedef __attribute__((ext_vector_type(8))) unsigned short u16x8;
typedef __attribute__((ext_vector_type(8))) __bf16 bf16x8;
typedef __attribute__((ext_vector_type(4))) float f32x4;

#define MFMA16(a, b, c) __builtin_amdgcn_mfma_f32_16x16x32_bf16((a), (b), (c), 0, 0, 0)

__device__ __forceinline__ u16 f2bf(float f) {
  uint32_t u = __builtin_bit_cast(uint32_t, f);
  u += 0x7FFFu + ((u >> 16) & 1u);
  return (u16)(u >> 16);
}
__device__ __forceinline__ float bf2f(u16 h) {
  return __builtin_bit_cast(float, (uint32_t)h << 16);
}

typedef const __attribute__((address_space(1))) void gv_t;
typedef __attribute__((address_space(3))) void lv_t;
__device__ __forceinline__ void gload16(const void* g, void* l) {
  __builtin_amdgcn_global_load_lds((gv_t*)g, (lv_t*)l, 16, 0, 0);
}

// ---------------- f32 -> bf16 convert (vectorized) ----------------
__global__ void cvt_f32_to_bf16(const float* __restrict__ in, u16* __restrict__ out, int n4) {
  int i = blockIdx.x * 256 + threadIdx.x;
  if (i >= n4) return;
  float4 v = ((const float4*)in)[i];
  u16x4 o;
  o[0] = f2bf(v.x); o[1] = f2bf(v.y); o[2] = f2bf(v.z); o[3] = f2bf(v.w);
  ((u16x4*)out)[i] = o;
}

// ------------- transpose + convert: W[2048][2048] f32 -> Wt bf16 [N][K] -------------
__global__ void transpose_cvt(const float* __restrict__ in, u16* __restrict__ out) {
  __shared__ float tile[32][33];
  const int bx = blockIdx.x, by = blockIdx.y;
  const int tx = threadIdx.x, ty = threadIdx.y;
#pragma unroll
  for (int i = 0; i < 32; i += 8)
    tile[ty + i][tx] = in[(size_t)(by * 32 + ty + i) * 2048 + bx * 32 + tx];
  __syncthreads();
#pragma unroll
  for (int i = 0; i < 32; i += 8)
    out[(size_t)(bx * 32 + ty + i) * 2048 + by * 32 + tx] = f2bf(tile[tx][ty + i]);
}

// ------------- RoPE in-place on bf16 [B,S,H,dk], pairs interleaved -------------
__global__ void rope_kernel(u16* __restrict__ X, const int* __restrict__ pos, float oscale) {
  const size_t idx = (size_t)blockIdx.x * 256 + threadIdx.x;  // pair id, 2^22 total
  const int i = (int)(idx & 63);
  const int h = (int)((idx >> 6) & 15);
  const int s = (int)((idx >> 10) & 2047);
  const int b = (int)(idx >> 21);
  const float p = (float)pos[b * 2048 + s];
  // theta^(-i/64) = exp2(-i/64 * log2(10000))
  const float freq = exp2f((float)i * -0.2076205059304601f);
  const float ang = p * freq;
  float sn, cs;
  sincosf(ang, &sn, &cs);
  uint32_t* ptr = (uint32_t*)(X + ((size_t)(b * 2048 + s)) * 2048 + h * 128 + 2 * i);
  const uint32_t v = *ptr;
  const float e = bf2f((u16)(v & 0xffffu));
  const float o = bf2f((u16)(v >> 16));
  const u16 re = f2bf((e * cs - o * sn) * oscale);
  const u16 ro = f2bf((e * sn + o * cs) * oscale);
  *ptr = (uint32_t)re | ((uint32_t)ro << 16);
}

// ------------- bf16 GEMM: C[M,N] = A[M,K] * Bt[N,K]^T  (m97-style 128x128, BK=64) -------------
template <bool OUTF32>
__global__ __launch_bounds__(256) void gemm_bf16(const u16* __restrict__ A,
                                                 const u16* __restrict__ Bt,
                                                 void* __restrict__ Cv) {
  constexpr int N = 2048, K = 2048;
  __shared__ u16 As[128 * 64];
  __shared__ u16 Bs[128 * 64];
  const int tid = threadIdx.x, lane = tid & 63, wid = tid >> 6;
  const int bm = blockIdx.y * 128, bn = blockIdx.x * 128;
  const int wr = wid >> 1, wc = wid & 1;

  f32x4 acc[4][4];
  const f32x4 z4 = {0.f, 0.f, 0.f, 0.f};
#pragma unroll
  for (int i = 0; i < 4; ++i)
#pragma unroll
    for (int j = 0; j < 4; ++j) acc[i][j] = z4;

  const int srow = lane >> 3;        // row within 8-row chunk
  const int scol = (lane & 7) * 8;   // element col within BK=64

  for (int k0 = 0; k0 < K; k0 += 64) {
    __syncthreads();
#pragma unroll
    for (int c = 0; c < 4; ++c) {
      const int chunk = wid * 4 + c;  // 0..15, each = 8 rows x 64 cols = 1KB
      const int r = chunk * 8 + srow;
      gload16(A + (size_t)(bm + r) * K + k0 + scol, (char*)As + chunk * 1024);
      gload16(Bt + (size_t)(bn + r) * K + k0 + scol, (char*)Bs + chunk * 1024);
    }
    __syncthreads();
#pragma unroll
    for (int kk = 0; kk < 64; kk += 32) {
      bf16x8 a[4], b[4];
#pragma unroll
      for (int i = 0; i < 4; ++i) {
        a[i] = *(const bf16x8*)(As + (wr * 64 + i * 16 + (lane & 15)) * 64 + kk + (lane >> 4) * 8);
        b[i] = *(const bf16x8*)(Bs + (wc * 64 + i * 16 + (lane & 15)) * 64 + kk + (lane >> 4) * 8);
      }
#pragma unroll
      for (int i = 0; i < 4; ++i)
#pragma unroll
        for (int j = 0; j < 4; ++j) acc[i][j] = MFMA16(a[i], b[j], acc[i][j]);
    }
  }

  const int r0 = bm + wr * 64 + (lane >> 4) * 4;
  const int c0 = bn + wc * 64 + (lane & 15);
  if constexpr (OUTF32) {
    float* C = (float*)Cv;
#pragma unroll
    for (int i = 0; i < 4; ++i)
#pragma unroll
      for (int j = 0; j < 4; ++j)
#pragma unroll
        for (int r = 0; r < 4; ++r)
          C[(size_t)(r0 + i * 16 + r) * N + c0 + j * 16] = acc[i][j][r];
  } else {
    u16* C = (u16*)Cv;
#pragma unroll
    for (int i = 0; i < 4; ++i)
#pragma unroll
      for (int j = 0; j < 4; ++j)
#pragma unroll
        for (int r = 0; r < 4; ++r)
          C[(size_t)(r0 + i * 16 + r) * N + c0 + j * 16] = f2bf(acc[i][j][r]);
  }
}

// ------------- causal flash attention, bf16 in [B,S,H,dk], 4 waves x 16 q-rows, KVBLK=64 -------------
__global__ __launch_bounds__(256) void flash_attn(const u16* __restrict__ Qb, const u16* __restrict__ Kb,
                                                  const u16* __restrict__ Vb, u16* __restrict__ Ob) {
  constexpr int S = 2048, HD = 2048, DK = 128;
  const int qt = (int)gridDim.x - 1 - (int)blockIdx.x;  // heavy tiles dispatch first
  const int bh = blockIdx.y;
  const int b = bh >> 4, h = bh & 15;
  const int tid = threadIdx.x, lane = tid & 63, wid = tid >> 6;
  const int q0 = qt * 64;

  __shared__ u16 Vt[128 * 64];      // V^T tile, swizzled
  __shared__ u16 Pl[4][16 * 64];    // per-wave P tile, swizzled

  const size_t base = (size_t)b * S * HD + (size_t)h * DK;
  const u16* Qp = Qb + base;
  const u16* Kp = Kb + base;
  const u16* Vp = Vb + base;
  u16* Op = Ob + base;

  // Q fragments (A operand): row = lane&15, k-chunk = (lane>>4)*8
  const int qrA = q0 + wid * 16 + (lane & 15);
  bf16x8 qf[4];
#pragma unroll
  for (int kb = 0; kb < 4; ++kb)
    qf[kb] = *(const bf16x8*)(Qp + (size_t)qrA * HD + kb * 32 + (lane >> 4) * 8);

  const f32x4 z4 = {0.f, 0.f, 0.f, 0.f};
  f32x4 accO[8];
#pragma unroll
  for (int d = 0; d < 8; ++d) accO[d] = z4;
  float m_r[4] = {-INFINITY, -INFINITY, -INFINITY, -INFINITY};
  float l_r[4] = {0.f, 0.f, 0.f, 0.f};

  const int vc = (tid & 3) * 32;  // d-chunk base (32 wide)
  const int vp = tid >> 2;        // kv row 0..63
  const int qrC = q0 + wid * 16 + (lane >> 4) * 4;  // C-layout row base

  for (int t = 0; t <= qt; ++t) {
    const int kv0 = t * 64;
    __syncthreads();  // prior PV reads of Vt done

    // stage V^T into LDS (swizzled rows of 128B)
    {
      const u16* vrow = Vp + (size_t)(kv0 + vp) * HD + vc;
#pragma unroll
      for (int u = 0; u < 4; ++u) {
        u16x8 v = *(const u16x8*)(vrow + u * 8);
#pragma unroll
        for (int e = 0; e < 8; ++e) {
          const int d = vc + u * 8 + e;
          const int byteoff = (d * 128 + vp * 2) ^ ((d & 7) << 4);
          *(u16*)((char*)Vt + byteoff) = v[e];
        }
      }
    }

    // S = Q K^T  (K fragments straight from global; L2-resident)
    f32x4 accS[4];
#pragma unroll
    for (int nb = 0; nb < 4; ++nb) accS[nb] = z4;
#pragma unroll
    for (int nb = 0; nb < 4; ++nb) {
      const u16* krow = Kp + (size_t)(kv0 + nb * 16 + (lane & 15)) * HD + (lane >> 4) * 8;
#pragma unroll
      for (int kb = 0; kb < 4; ++kb) {
        bf16x8 kf = *(const bf16x8*)(krow + kb * 32);
        accS[nb] = MFMA16(qf[kb], kf, accS[nb]);
      }
    }

    // causal mask on the diagonal tile
    if (t == qt) {
#pragma unroll
      for (int nb = 0; nb < 4; ++nb) {
        const int kv = kv0 + nb * 16 + (lane & 15);
#pragma unroll
        for (int j = 0; j < 4; ++j)
          if (kv > qrC + j) accS[nb][j] = -INFINITY;
      }
    }

    // online softmax (rows live across 16-lane groups; reg j = row (lane>>4)*4+j)
#pragma unroll
    for (int j = 0; j < 4; ++j) {
      float mx = fmaxf(fmaxf(accS[0][j], accS[1][j]), fmaxf(accS[2][j], accS[3][j]));
#pragma unroll
      for (int off = 1; off < 16; off <<= 1) mx = fmaxf(mx, __shfl_xor(mx, off));
      const float mn = fmaxf(m_r[j], mx);
      const float sc = __expf(m_r[j] - mn);
      m_r[j] = mn;
      float s = 0.f;
#pragma unroll
      for (int nb = 0; nb < 4; ++nb) {
        const float p = __expf(accS[nb][j] - mn);
        accS[nb][j] = p;
        s += p;
      }
#pragma unroll
      for (int off = 1; off < 16; off <<= 1) s += __shfl_xor(s, off);
      l_r[j] = l_r[j] * sc + s;
#pragma unroll
      for (int d = 0; d < 8; ++d) accO[d][j] *= sc;
    }

    // write P (bf16) to per-wave LDS, swizzled
    u16* Pw = &Pl[wid][0];
#pragma unroll
    for (int nb = 0; nb < 4; ++nb)
#pragma unroll
      for (int j = 0; j < 4; ++j) {
        const int row = (lane >> 4) * 4 + j;
        const int col = nb * 16 + (lane & 15);
        const int byteoff = (row * 128 + col * 2) ^ ((row & 7) << 4);
        *(u16*)((char*)Pw + byteoff) = f2bf(accS[nb][j]);
      }

    __syncthreads();  // Vt staged by all waves

    // O += P V
#pragma unroll
    for (int kb2 = 0; kb2 < 2; ++kb2) {
      const int arow = lane & 15;
      const int abyte = (arow * 128 + (kb2 * 32 + (lane >> 4) * 8) * 2) ^ ((arow & 7) << 4);
      bf16x8 pa = *(const bf16x8*)((char*)Pw + abyte);
#pragma unroll
      for (int db = 0; db < 8; ++db) {
        const int vr = db * 16 + (lane & 15);
        const int vbyte = (vr * 128 + (kb2 * 32 + (lane >> 4) * 8) * 2) ^ ((vr & 7) << 4);
        bf16x8 vf = *(const bf16x8*)((char*)Vt + vbyte);
        accO[db] = MFMA16(pa, vf, accO[db]);
      }
    }
  }

  // epilogue: normalize and store bf16
  float inv[4];
#pragma unroll
  for (int j = 0; j < 4; ++j) inv[j] = 1.f / l_r[j];
#pragma unroll
  for (int db = 0; db < 8; ++db)
#pragma unroll
    for (int j = 0; j < 4; ++j) {
      const int row = qrC + j;
      Op[(size_t)row * HD + db * 16 + (lane & 15)] = f2bf(accO[db][j] * inv[j]);
    }
}

extern "C" void kernel_launch(void* const* d_in, const int* in_sizes, int n_in,
                              void* d_out, int out_size, void* d_ws, size_t ws_size,
                              hipStream_t stream) {
  const float* x  = (const float*)d_in[0];
  const int*   tp = (const int*)d_in[1];
  const float* WQ = (const float*)d_in[2];
  const float* WK = (const float*)d_in[3];
  const float* WV = (const float*)d_in[4];
  const float* WO = (const float*)d_in[5];

  const size_t MB = 1024 * 1024;
  if (ws_size < 112 * MB) return;  // need 112 MiB scratch
  char* ws = (char*)d_ws;
  u16* xb  = (u16*)(ws + 0 * MB);    // x bf16 [4096][2048]           16 MiB
  u16* wqt = (u16*)(ws + 16 * MB);   // WQ^T bf16 [2048][2048]         8 MiB
  u16* wkt = (u16*)(ws + 24 * MB);
  u16* wvt = (u16*)(ws + 32 * MB);
  u16* wot = (u16*)(ws + 40 * MB);
  u16* Qb  = (u16*)(ws + 48 * MB);   // [B,S,H,dk] bf16               16 MiB
  u16* Kb  = (u16*)(ws + 64 * MB);
  u16* Vb  = (u16*)(ws + 80 * MB);
  u16* Obf = (u16*)(ws + 96 * MB);   // attention out [B,S,D] bf16    16 MiB

  // 1. conversions
  cvt_f32_to_bf16<<<8192, 256, 0, stream>>>(x, xb, 2097152);
  {
    dim3 g(64, 64), blk(32, 8);
    transpose_cvt<<<g, blk, 0, stream>>>(WQ, wqt);
    transpose_cvt<<<g, blk, 0, stream>>>(WK, wkt);
    transpose_cvt<<<g, blk, 0, stream>>>(WV, wvt);
    transpose_cvt<<<g, blk, 0, stream>>>(WO, wot);
  }

  // 2. projections (bf16 out, [B,S,H,dk] == row-major [4096][2048])
  {
    dim3 g(16, 32);
    gemm_bf16<false><<<g, 256, 0, stream>>>(xb, wqt, (void*)Qb);
    gemm_bf16<false><<<g, 256, 0, stream>>>(xb, wkt, (void*)Kb);
    gemm_bf16<false><<<g, 256, 0, stream>>>(xb, wvt, (void*)Vb);
  }

  // 3. RoPE (fold 1/sqrt(d_k) into Q)
  rope_kernel<<<16384, 256, 0, stream>>>(Qb, tp, 0.08838834764831845f);
  rope_kernel<<<16384, 256, 0, stream>>>(Kb, tp, 1.0f);

  // 4. causal flash attention
  {
    dim3 g(32, 32);
    flash_attn<<<g, 256, 0, stream>>>(Qb, Kb, Vb, Obf);
  }

  // 5. output projection -> f32 d_out
  {
    dim3 g(16, 32);
    gemm_bf16<true><<<g, 256, 0, stream>>>(Obf, wot, d_out);
  }
}

// Round 3
// 351.354 us; speedup vs baseline: 1.5303x; 1.5303x over previous
//
#include <hip/hip_runtime.h>
#include <hip/hip_bf16.h>
#include <cstdint>
#include <cstddef>

typedef unsigned short u16;
typedef __attribute__((ext_vector_type(4))) unsigned short u16x4;
typedef __attribute__((ext_vector_type(8))) unsigned short u16x8;
typedef __attribute__((ext_vector_type(8))) __bf16 bf16x8;
typedef __attribute__((ext_vector_type(4))) float f32x4;

#define MFMA16(a, b, c) __builtin_amdgcn_mfma_f32_16x16x32_bf16((a), (b), (c), 0, 0, 0)

__device__ __forceinline__ u16 f2bf(float f) {
  uint32_t u = __builtin_bit_cast(uint32_t, f);
  u += 0x7FFFu + ((u >> 16) & 1u);
  return (u16)(u >> 16);
}
__device__ __forceinline__ float bf2f(u16 h) {
  return __builtin_bit_cast(float, (uint32_t)h << 16);
}

typedef const __attribute__((address_space(1))) void gv_t;
typedef __attribute__((address_space(3))) void lv_t;
__device__ __forceinline__ void gload16(const void* g, void* l) {
  __builtin_amdgcn_global_load_lds((gv_t*)g, (lv_t*)l, 16, 0, 0);
}

// ---------------- f32 -> bf16 convert (vectorized) ----------------
__global__ void cvt_f32_to_bf16(const float* __restrict__ in, u16* __restrict__ out, int n4) {
  int i = blockIdx.x * 256 + threadIdx.x;
  if (i >= n4) return;
  float4 v = ((const float4*)in)[i];
  u16x4 o;
  o[0] = f2bf(v.x); o[1] = f2bf(v.y); o[2] = f2bf(v.z); o[3] = f2bf(v.w);
  ((u16x4*)out)[i] = o;
}

// ------------- transpose + convert: W[2048][2048] f32 -> Wt bf16 [N][K] -------------
__global__ void transpose_cvt(const float* __restrict__ in, u16* __restrict__ out) {
  __shared__ float tile[32][33];
  const int bx = blockIdx.x, by = blockIdx.y;
  const int tx = threadIdx.x, ty = threadIdx.y;
#pragma unroll
  for (int i = 0; i < 32; i += 8)
    tile[ty + i][tx] = in[(size_t)(by * 32 + ty + i) * 2048 + bx * 32 + tx];
  __syncthreads();
#pragma unroll
  for (int i = 0; i < 32; i += 8)
    out[(size_t)(bx * 32 + ty + i) * 2048 + by * 32 + tx] = f2bf(tile[tx][ty + i]);
}

// ------------- per-head transpose of V: bf16 [B*S][H*dk] -> VT [B,H,dk,S] -------------
__global__ void vtrans(const u16* __restrict__ in, u16* __restrict__ out) {
  __shared__ u16 tile[32][34];
  const int bx = blockIdx.x, by = blockIdx.y;  // bx: col tile (64), by: row tile (128)
  const int tx = threadIdx.x, ty = threadIdx.y;
#pragma unroll
  for (int i = 0; i < 32; i += 8)
    tile[ty + i][tx] = in[(size_t)(by * 32 + ty + i) * 2048 + bx * 32 + tx];
  __syncthreads();
#pragma unroll
  for (int i = 0; i < 32; i += 8) {
    const int c = bx * 32 + ty + i;      // 0..2047 = h*128 + d
    const int token = by * 32 + tx;      // 0..4095 = b*2048 + s
    // value needed is in[token][c] == tile[tx][ty+i]  (transposed read!)
    out[(((size_t)(token >> 11) * 16 + (c >> 7)) * 128 + (c & 127)) * 2048 + (token & 2047)] =
        tile[tx][ty + i];
  }
}

// ------------- RoPE in-place on Q and K (bf16 [B,S,H,dk]), 1/sqrt(dk) folded into Q -------------
__global__ void rope2(u16* __restrict__ Q, u16* __restrict__ K, const int* __restrict__ pos) {
  const size_t idx = (size_t)blockIdx.x * 256 + threadIdx.x;  // pair id, 2^22 total
  const int i = (int)(idx & 63);
  const int s = (int)((idx >> 10) & 2047);
  const int b = (int)(idx >> 21);
  const float p = (float)pos[b * 2048 + s];
  const float freq = exp2f((float)i * -0.2076205059304601f);  // theta^(-i/64)
  float sn, cs;
  sincosf(p * freq, &sn, &cs);
  const size_t off = ((idx >> 10) << 11) + (((idx >> 6) & 15) << 7) + 2 * i;  // (b*2048+s)*2048 + h*128 + 2i
  {
    uint32_t* ptr = (uint32_t*)(Q + off);
    const uint32_t v = *ptr;
    const float e = bf2f((u16)(v & 0xffffu)), o = bf2f((u16)(v >> 16));
    const float sc = 0.08838834764831845f;
    *ptr = (uint32_t)f2bf((e * cs - o * sn) * sc) | ((uint32_t)f2bf((e * sn + o * cs) * sc) << 16);
  }
  {
    uint32_t* ptr = (uint32_t*)(K + off);
    const uint32_t v = *ptr;
    const float e = bf2f((u16)(v & 0xffffu)), o = bf2f((u16)(v >> 16));
    *ptr = (uint32_t)f2bf(e * cs - o * sn) | ((uint32_t)f2bf(e * sn + o * cs) << 16);
  }
}

// ------------- bf16 GEMM: C[M,N] = A[M,K] * Bt[N,K]^T  (m97-style 128x128, BK=64) -------------
template <bool OUTF32>
__global__ __launch_bounds__(256) void gemm_bf16(const u16* __restrict__ A,
                                                 const u16* __restrict__ Bt,
                                                 void* __restrict__ Cv) {
  constexpr int N = 2048, K = 2048;
  __shared__ u16 As[128 * 64];
  __shared__ u16 Bs[128 * 64];
  const int tid = threadIdx.x, lane = tid & 63, wid = tid >> 6;
  const int bm = blockIdx.y * 128, bn = blockIdx.x * 128;
  const int wr = wid >> 1, wc = wid & 1;

  f32x4 acc[4][4];
  const f32x4 z4 = {0.f, 0.f, 0.f, 0.f};
#pragma unroll
  for (int i = 0; i < 4; ++i)
#pragma unroll
    for (int j = 0; j < 4; ++j) acc[i][j] = z4;

  const int srow = lane >> 3;
  const int scol = (lane & 7) * 8;

  for (int k0 = 0; k0 < K; k0 += 64) {
    __syncthreads();
#pragma unroll
    for (int c = 0; c < 4; ++c) {
      const int chunk = wid * 4 + c;
      const int r = chunk * 8 + srow;
      gload16(A + (size_t)(bm + r) * K + k0 + scol, (char*)As + chunk * 1024);
      gload16(Bt + (size_t)(bn + r) * K + k0 + scol, (char*)Bs + chunk * 1024);
    }
    __syncthreads();
#pragma unroll
    for (int kk = 0; kk < 64; kk += 32) {
      bf16x8 a[4], b[4];
#pragma unroll
      for (int i = 0; i < 4; ++i) {
        a[i] = *(const bf16x8*)(As + (wr * 64 + i * 16 + (lane & 15)) * 64 + kk + (lane >> 4) * 8);
        b[i] = *(const bf16x8*)(Bs + (wc * 64 + i * 16 + (lane & 15)) * 64 + kk + (lane >> 4) * 8);
      }
#pragma unroll
      for (int i = 0; i < 4; ++i)
#pragma unroll
        for (int j = 0; j < 4; ++j) acc[i][j] = MFMA16(a[i], b[j], acc[i][j]);
    }
  }

  const int r0 = bm + wr * 64 + (lane >> 4) * 4;
  const int c0 = bn + wc * 64 + (lane & 15);
  if constexpr (OUTF32) {
    float* C = (float*)Cv;
#pragma unroll
    for (int i = 0; i < 4; ++i)
#pragma unroll
      for (int j = 0; j < 4; ++j)
#pragma unroll
        for (int r = 0; r < 4; ++r)
          C[(size_t)(r0 + i * 16 + r) * N + c0 + j * 16] = acc[i][j][r];
  } else {
    u16* C = (u16*)Cv;
#pragma unroll
    for (int i = 0; i < 4; ++i)
#pragma unroll
      for (int j = 0; j < 4; ++j)
#pragma unroll
        for (int r = 0; r < 4; ++r)
          C[(size_t)(r0 + i * 16 + r) * N + c0 + j * 16] = f2bf(acc[i][j][r]);
  }
}

// ------------- causal flash attention v2: 4 waves x 32 q-rows (QTILE=128), KVBLK=64 -------------
// K and V^T staged in LDS via global_load_lds with XOR-swizzled layout
// (pre-swizzled global source, linear LDS dest). V^T comes from pre-transposed VT [B,H,dk,S].
__global__ __launch_bounds__(256, 2) void flash_attn2(const u16* __restrict__ Qb,
                                                      const u16* __restrict__ Kb,
                                                      const u16* __restrict__ VT,
                                                      u16* __restrict__ Ob) {
  constexpr int S = 2048, HD = 2048;
  // XCD-aware decode: each XCD owns 4 heads (K/V working set ~4MB = its L2); heavy qt first.
  const int g = (int)blockIdx.x;
  const int xcd = g & 7, slot = g >> 3;
  const int bh = xcd * 4 + (slot & 3);
  const int qt = 15 - (slot >> 2);
  const int b = bh >> 4, h = bh & 15;
  const int tid = threadIdx.x, lane = tid & 63, wid = tid >> 6;
  const int q0 = qt * 128;

  __shared__ u16 Ks[64 * 128];   // [kv][d], row 256B, swizzled: byte = kv*256 + ((c16^(kv&7))<<4)
  __shared__ u16 Vs[128 * 64];   // [d][kv], row 128B, swizzled: byte = d*128 + ((c16^(d&7))<<4)
  __shared__ u16 Ps[4][32 * 64]; // per-wave P [q][kv], row 128B, swizzled

  const size_t base = (size_t)b * S * HD + (size_t)h * 128;
  const u16* Qp = Qb + base;
  const u16* Kp = Kb + base;
  const u16* VTp = VT + (size_t)bh * 128 * S;
  u16* Op = Ob + base;

  // Q fragments (A operand): row = lane&15, k-chunk = (lane>>4)*8
  bf16x8 qf[2][4];
  {
    const int qr = q0 + wid * 32 + (lane & 15);
    const int kc = (lane >> 4) * 8;
#pragma unroll
    for (int rb = 0; rb < 2; ++rb)
#pragma unroll
      for (int kb = 0; kb < 4; ++kb)
        qf[rb][kb] = *(const bf16x8*)(Qp + (size_t)(qr + rb * 16) * HD + kb * 32 + kc);
  }

  const f32x4 z4 = {0.f, 0.f, 0.f, 0.f};
  f32x4 accO[2][8];
#pragma unroll
  for (int rb = 0; rb < 2; ++rb)
#pragma unroll
    for (int d = 0; d < 8; ++d) accO[rb][d] = z4;
  float m_r[2][4], l_r[2][4];
#pragma unroll
  for (int rb = 0; rb < 2; ++rb)
#pragma unroll
    for (int j = 0; j < 4; ++j) { m_r[rb][j] = -INFINITY; l_r[rb][j] = 0.f; }

  const int nsteps = 2 * (qt + 1);
  for (int t = 0; t < nsteps; ++t) {
    const int kv0 = t * 64;
    __syncthreads();  // prior step's LDS reads done (drains vmcnt too)

    // ---- stage K tile (16KB) + V^T tile (16KB); swizzle via pre-swizzled global source ----
#pragma unroll
    for (int c = 0; c < 4; ++c) {
      const int ch = wid * 4 + c;
      {  // K: chunk = 4 rows x 128 d
        const int kv = ch * 4 + (lane >> 4);
        const int c16 = (lane & 15) ^ (kv & 7);
        gload16(Kp + (size_t)(kv0 + kv) * HD + c16 * 8, (char*)Ks + ch * 1024);
      }
      {  // V^T: chunk = 8 rows(d) x 64 kv
        const int d = ch * 8 + (lane >> 3);
        const int c16 = (lane & 7) ^ (d & 7);
        gload16(VTp + (size_t)d * S + kv0 + c16 * 8, (char*)Vs + ch * 1024);
      }
    }
    __syncthreads();  // staging visible to all waves

    // waves whose q-rows are all < kv0 contribute nothing on this (diagonal) step
    const bool skip = (kv0 > q0 + wid * 32 + 31);
    if (!skip) {
      f32x4 accS[2][4];
#pragma unroll
      for (int rb = 0; rb < 2; ++rb)
#pragma unroll
        for (int nb = 0; nb < 4; ++nb) accS[rb][nb] = z4;

      // ---- S = Q K^T ----
#pragma unroll
      for (int nb = 0; nb < 4; ++nb) {
        const int kv = nb * 16 + (lane & 15);
#pragma unroll
        for (int kb = 0; kb < 4; ++kb) {
          const int c16 = (kb * 4 + (lane >> 4)) ^ (kv & 7);
          bf16x8 kf = *(const bf16x8*)((char*)Ks + kv * 256 + c16 * 16);
          accS[0][nb] = MFMA16(qf[0][kb], kf, accS[0][nb]);
          accS[1][nb] = MFMA16(qf[1][kb], kf, accS[1][nb]);
        }
      }

      // ---- causal mask (only the last two steps of a block touch the diagonal) ----
      if (kv0 + 63 > q0) {
#pragma unroll
        for (int rb = 0; rb < 2; ++rb)
#pragma unroll
          for (int nb = 0; nb < 4; ++nb) {
            const int kv = kv0 + nb * 16 + (lane & 15);
            const int qrow = q0 + wid * 32 + rb * 16 + (lane >> 4) * 4;
#pragma unroll
            for (int j = 0; j < 4; ++j)
              if (kv > qrow + j) accS[rb][nb][j] = -INFINITY;
          }
      }

      // ---- online softmax (row = (lane>>4)*4+j within 16-lane group) + P write ----
      u16* Pw = &Ps[wid][0];
#pragma unroll
      for (int rb = 0; rb < 2; ++rb)
#pragma unroll
        for (int j = 0; j < 4; ++j) {
          float mx = fmaxf(fmaxf(accS[rb][0][j], accS[rb][1][j]),
                           fmaxf(accS[rb][2][j], accS[rb][3][j]));
#pragma unroll
          for (int off = 1; off < 16; off <<= 1) mx = fmaxf(mx, __shfl_xor(mx, off));
          const float mn = fmaxf(m_r[rb][j], mx);
          const float sc = __expf(m_r[rb][j] - mn);
          m_r[rb][j] = mn;
          float s = 0.f;
#pragma unroll
          for (int nb = 0; nb < 4; ++nb) {
            const float p = __expf(accS[rb][nb][j] - mn);
            accS[rb][nb][j] = p;
            s += p;
          }
#pragma unroll
          for (int off = 1; off < 16; off <<= 1) s += __shfl_xor(s, off);
          l_r[rb][j] = l_r[rb][j] * sc + s;
#pragma unroll
          for (int db = 0; db < 8; ++db) accO[rb][db][j] *= sc;
          const int ql = rb * 16 + (lane >> 4) * 4 + j;
#pragma unroll
          for (int nb = 0; nb < 4; ++nb) {
            const int col = nb * 16 + (lane & 15);
            const int byteoff = ql * 128 + ((((col >> 3) ^ (ql & 7))) << 4) + (col & 7) * 2;
            *(u16*)((char*)Pw + byteoff) = f2bf(accS[rb][nb][j]);
          }
        }

      // ---- O += P V ----
#pragma unroll
      for (int kb2 = 0; kb2 < 2; ++kb2) {
        bf16x8 pa[2];
#pragma unroll
        for (int rb = 0; rb < 2; ++rb) {
          const int ql = rb * 16 + (lane & 15);
          const int c16 = (kb2 * 4 + (lane >> 4)) ^ (ql & 7);
          pa[rb] = *(const bf16x8*)((char*)Pw + ql * 128 + c16 * 16);
        }
#pragma unroll
        for (int db = 0; db < 8; ++db) {
          const int d = db * 16 + (lane & 15);
          const int c16 = (kb2 * 4 + (lane >> 4)) ^ (d & 7);
          bf16x8 vf = *(const bf16x8*)((char*)Vs + d * 128 + c16 * 16);
          accO[0][db] = MFMA16(pa[0], vf, accO[0][db]);
          accO[1][db] = MFMA16(pa[1], vf, accO[1][db]);
        }
      }
    }
  }

  // ---- epilogue: normalize, store bf16 ----
  float inv[2][4];
#pragma unroll
  for (int rb = 0; rb < 2; ++rb)
#pragma unroll
    for (int j = 0; j < 4; ++j) inv[rb][j] = 1.f / l_r[rb][j];
#pragma unroll
  for (int rb = 0; rb < 2; ++rb)
#pragma unroll
    for (int db = 0; db < 8; ++db)
#pragma unroll
      for (int j = 0; j < 4; ++j) {
        const int row = q0 + wid * 32 + rb * 16 + (lane >> 4) * 4 + j;
        Op[(size_t)row * HD + db * 16 + (lane & 15)] = f2bf(accO[rb][db][j] * inv[rb][j]);
      }
}

extern "C" void kernel_launch(void* const* d_in, const int* in_sizes, int n_in,
                              void* d_out, int out_size, void* d_ws, size_t ws_size,
                              hipStream_t stream) {
  const float* x  = (const float*)d_in[0];
  const int*   tp = (const int*)d_in[1];
  const float* WQ = (const float*)d_in[2];
  const float* WK = (const float*)d_in[3];
  const float* WV = (const float*)d_in[4];
  const float* WO = (const float*)d_in[5];

  const size_t MB = 1024 * 1024;
  if (ws_size < 112 * MB) return;
  char* ws = (char*)d_ws;
  u16* xb  = (u16*)(ws + 0 * MB);    // x bf16 [4096][2048]; reused as VT after V GEMM
  u16* wqt = (u16*)(ws + 16 * MB);
  u16* wkt = (u16*)(ws + 24 * MB);
  u16* wvt = (u16*)(ws + 32 * MB);
  u16* wot = (u16*)(ws + 40 * MB);
  u16* Qb  = (u16*)(ws + 48 * MB);   // [B,S,H,dk] bf16
  u16* Kb  = (u16*)(ws + 64 * MB);
  u16* Vb  = (u16*)(ws + 80 * MB);
  u16* Obf = (u16*)(ws + 96 * MB);
  u16* VTb = xb;                     // V^T [B,H,dk,S] bf16 (xb dead after projections)

  // 1. conversions
  cvt_f32_to_bf16<<<8192, 256, 0, stream>>>(x, xb, 2097152);
  {
    dim3 g(64, 64), blk(32, 8);
    transpose_cvt<<<g, blk, 0, stream>>>(WQ, wqt);
    transpose_cvt<<<g, blk, 0, stream>>>(WK, wkt);
    transpose_cvt<<<g, blk, 0, stream>>>(WV, wvt);
    transpose_cvt<<<g, blk, 0, stream>>>(WO, wot);
  }

  // 2. projections
  {
    dim3 g(16, 32);
    gemm_bf16<false><<<g, 256, 0, stream>>>(xb, wqt, (void*)Qb);
    gemm_bf16<false><<<g, 256, 0, stream>>>(xb, wkt, (void*)Kb);
    gemm_bf16<false><<<g, 256, 0, stream>>>(xb, wvt, (void*)Vb);
  }

  // 3. RoPE on Q (scaled by 1/sqrt(dk)) and K, one pass
  rope2<<<16384, 256, 0, stream>>>(Qb, Kb, tp);

  // 4. per-head transpose of V (xb is dead now)
  {
    dim3 g(64, 128), blk(32, 8);
    vtrans<<<g, blk, 0, stream>>>(Vb, VTb);
  }

  // 5. causal flash attention
  flash_attn2<<<512, 256, 0, stream>>>(Qb, Kb, VTb, Obf);

  // 6. output projection -> f32 d_out
  {
    dim3 g(16, 32);
    gemm_bf16<true><<<g, 256, 0, stream>>>(Obf, wot, d_out);
  }
}